// Round 8
// baseline (247.403 us; speedup 1.0000x reference)
//
#include <hip/hip_runtime.h>

#define NXD 128
#define NYD 128
#define SRC_XD 64
#define SRC_YD 64
#define T_STEPSD 256
#define BATCHD 8
#define N_PROBESD 4

typedef float v2f __attribute__((ext_vector_type(2)));

// DPP cross-lane single shifts across the full wave64.
// WAVE_SHR1 (0x138): lane i <- lane i-1, lane0 -> 0 (bound_ctrl)
// WAVE_SHL1 (0x130): lane i <- lane i+1, lane63 -> 0
// Zero-fill matches the conv 'SAME' zero padding at col -1 / col 128.
__device__ __forceinline__ float dpp_from_lower(float v) {
    return __int_as_float(__builtin_amdgcn_update_dpp(0, __float_as_int(v), 0x138, 0xF, 0xF, true));
}
__device__ __forceinline__ float dpp_from_upper(float v) {
    return __int_as_float(__builtin_amdgcn_update_dpp(0, __float_as_int(v), 0x130, 0xF, 0xF, true));
}

// One row update (2 cells). k comes from LDS (ds_read_b64 at literal offset
// ri*512B off one shared address reg) instead of registers -- round 5/6/7
// showed the allocator AGPR-parks k0..k15 and pays 2 v_accvgpr_reads per ROW.
#define ROW(up, dn, Yr, Zr, ri) { \
    v2f lr; lr.x = dpp_from_lower((Yr).y); lr.y = dpp_from_upper((Yr).x); \
    const v2f kr = kcol[(ri) * 64]; \
    v2f ysw; ysw.x = (Yr).y; ysw.y = (Yr).x; \
    const v2f cross = lr + ysw; \
    const v2f lap = ((up) + (dn)) + cross - 4.0f * (Yr); \
    (Zr) = kr * lap + (C2v + K2v * (Zr)); \
}

// Wave-uniform 16-way register select (ro is an SGPR -> scalar branch tree).
#define PSEL(ro, Z, pv) switch (ro) { \
    case 0:  pv = (Z##0);  break; \
    case 1:  pv = (Z##1);  break; \
    case 2:  pv = (Z##2);  break; \
    case 3:  pv = (Z##3);  break; \
    case 4:  pv = (Z##4);  break; \
    case 5:  pv = (Z##5);  break; \
    case 6:  pv = (Z##6);  break; \
    case 7:  pv = (Z##7);  break; \
    case 8:  pv = (Z##8);  break; \
    case 9:  pv = (Z##9);  break; \
    case 10: pv = (Z##10); break; \
    case 11: pv = (Z##11); break; \
    case 12: pv = (Z##12); break; \
    case 13: pv = (Z##13); break; \
    case 14: pv = (Z##14); break; \
    default: pv = (Z##15); break; \
}

// One time step: Y = current (read-only), Z = previous, overwritten with new.
// Source add hardcodes (Z##0).x: SRC_XD & 15 == 0, SRC_YD even.
#define STEP(Y, Z, tt) { \
    const int buf_ = (tt) & 1, nb_ = buf_ ^ 1; \
    const v2f ra = *(const v2f*)&haloBot[buf_][wa][colb]; \
    const v2f rb = *(const v2f*)&haloTop[buf_][wb][colb]; \
    ROW(ra,    Y##1,  Y##0,  Z##0,  0) \
    ROW(Y##0,  Y##2,  Y##1,  Z##1,  1) \
    ROW(Y##1,  Y##3,  Y##2,  Z##2,  2) \
    ROW(Y##2,  Y##4,  Y##3,  Z##3,  3) \
    ROW(Y##3,  Y##5,  Y##4,  Z##4,  4) \
    ROW(Y##4,  Y##6,  Y##5,  Z##5,  5) \
    ROW(Y##5,  Y##7,  Y##6,  Z##6,  6) \
    ROW(Y##6,  Y##8,  Y##7,  Z##7,  7) \
    ROW(Y##7,  Y##9,  Y##8,  Z##8,  8) \
    ROW(Y##8,  Y##10, Y##9,  Z##9,  9) \
    ROW(Y##9,  Y##11, Y##10, Z##10, 10) \
    ROW(Y##10, Y##12, Y##11, Z##11, 11) \
    ROW(Y##11, Y##13, Y##12, Z##12, 12) \
    ROW(Y##12, Y##14, Y##13, Z##13, 13) \
    ROW(Y##13, Y##15, Y##14, Z##14, 14) \
    ROW(Y##14, rb,    Y##15, Z##15, 15) \
    if (has_src) { if (own_src) (Z##0).x += xs[tt]; } \
    if (whas0) { v2f pv; PSEL(pro0s, Z, pv) accv0 += pv * pv; } \
    if (whas1) { v2f pv; PSEL(pro1s, Z, pv) accv1 += pv * pv; } \
    if (whas2) { v2f pv; PSEL(pro2s, Z, pv) accv2 += pv * pv; } \
    if (whas3) { v2f pv; PSEL(pro3s, Z, pv) accv3 += pv * pv; } \
    *(v2f*)&haloTop[nb_][w][colb] = (Z##0); \
    *(v2f*)&haloBot[nb_][w][colb] = (Z##15); \
    __syncthreads(); \
}

// 512 threads = 8 waves = 2/EU = 1 block/CU (grid = 8 blocks, one per batch).
__global__ __launch_bounds__(512)
__attribute__((amdgpu_waves_per_eu(2, 2)))
void wave_sim(
        const float* __restrict__ x,        // (T,B)
        const float* __restrict__ c,        // (NX,NY)
        const int*   __restrict__ probes,   // (4,2) int
        float* __restrict__ partial,        // (B,4) in d_ws (+16 floats)
        unsigned*    cnt,                   // d_ws[0], poison-init 0xAAAAAAAA
        float* __restrict__ out)            // (4,)
{
    __shared__ float kLDS[NXD * NYD];       // KL*c^2, all 128 rows (64 KB)
    __shared__ float haloTop[2][9][NYD];    // band row R0;  [8] = zero ghost
    __shared__ float haloBot[2][9][NYD];    // band row R15; [8] = zero ghost
    __shared__ float xs[T_STEPSD];

    const int tid = threadIdx.x;
    const int w = tid >> 6;       // wave 0..7, owns rows 16w..16w+15
    const int l = tid & 63;       // lane, owns cols 2l, 2l+1
    const int b = blockIdx.x;

    const float dt = 0.5f, bdamp = 0.005f;
    const float denom = 1.0f / (dt * dt) + 0.5f * bdamp / dt;  // 4.005
    const float inv_denom = 1.0f / denom;
    const float C2 = 2.0f * inv_denom;
    const float K2 = (-1.0f - dt * bdamp) * inv_denom;
    const float KL = dt * dt * inv_denom;
    v2f C2v; C2v.x = C2; C2v.y = C2;
    v2f K2v; K2v.x = K2; K2v.y = K2;
    v2f zz; zz.x = 0.0f; zz.y = 0.0f;

    // populate k in LDS (coalesced), zero halos, stage x
    for (int i = tid; i < NXD * NYD; i += 512) {
        const float cv = c[i];
        kLDS[i] = KL * cv * cv;
    }
    for (int i = tid; i < 2 * 9 * NYD; i += 512) {
        ((float*)haloTop)[i] = 0.0f;
        ((float*)haloBot)[i] = 0.0f;
    }
    if (tid < T_STEPSD) xs[tid] = x[tid * BATCHD + b];

    const int colb = 2 * l;
    // per-wave k column pointer: element (row 16w+ri, col 2l) at kcol[ri*64]
    const v2f* kcol = (const v2f*)kLDS + (w * 16) * 64 + l;

    v2f a0 = zz, a1 = zz, a2 = zz, a3 = zz, a4 = zz, a5 = zz, a6 = zz, a7 = zz,
        a8 = zz, a9 = zz, a10 = zz, a11 = zz, a12 = zz, a13 = zz, a14 = zz, a15 = zz;
    v2f b0 = zz, b1 = zz, b2 = zz, b3 = zz, b4 = zz, b5 = zz, b6 = zz, b7 = zz,
        b8 = zz, b9 = zz, b10 = zz, b11 = zz, b12 = zz, b13 = zz, b14 = zz, b15 = zz;

    // probes (wave-uniform coordinates)
    const int px0 = probes[0] & 127, py0 = probes[1] & 127;
    const int px1 = probes[2] & 127, py1 = probes[3] & 127;
    const int px2 = probes[4] & 127, py2 = probes[5] & 127;
    const int px3 = probes[6] & 127, py3 = probes[7] & 127;
    const bool own0 = ((px0 >> 4) == w) && ((py0 >> 1) == l);
    const bool own1 = ((px1 >> 4) == w) && ((py1 >> 1) == l);
    const bool own2 = ((px2 >> 4) == w) && ((py2 >> 1) == l);
    const bool own3 = ((px3 >> 4) == w) && ((py3 >> 1) == l);
    const bool whas0 = __ballot(own0) != 0ULL;
    const bool whas1 = __ballot(own1) != 0ULL;
    const bool whas2 = __ballot(own2) != 0ULL;
    const bool whas3 = __ballot(own3) != 0ULL;
    const int pro0s = __builtin_amdgcn_readfirstlane(px0 & 15);
    const int pro1s = __builtin_amdgcn_readfirstlane(px1 & 15);
    const int pro2s = __builtin_amdgcn_readfirstlane(px2 & 15);
    const int pro3s = __builtin_amdgcn_readfirstlane(px3 & 15);
    const int pel0 = py0 & 1, pel1 = py1 & 1, pel2 = py2 & 1, pel3 = py3 & 1;
    v2f accv0 = zz, accv1 = zz, accv2 = zz, accv3 = zz;

    const bool has_src = (w == (SRC_XD >> 4));            // wave 4 (row 64 = its R0)
    const bool own_src = has_src && (l == (SRC_YD >> 1)); // SRC_YD even -> .x

    const int wa = (w == 0) ? 8 : w - 1;    // 8 = zero ghost slot
    const int wb = (w == 7) ? 8 : w + 1;

    __syncthreads();

#pragma unroll 1
    for (int t = 0; t < T_STEPSD; t += 2) {
        STEP(a, b, t)
        STEP(b, a, t + 1)
    }

    // publish this block's probe sums (agent scope: blocks land on different XCDs)
    if (own0) __hip_atomic_store(&partial[b * N_PROBESD + 0], pel0 ? accv0.y : accv0.x,
                                 __ATOMIC_RELAXED, __HIP_MEMORY_SCOPE_AGENT);
    if (own1) __hip_atomic_store(&partial[b * N_PROBESD + 1], pel1 ? accv1.y : accv1.x,
                                 __ATOMIC_RELAXED, __HIP_MEMORY_SCOPE_AGENT);
    if (own2) __hip_atomic_store(&partial[b * N_PROBESD + 2], pel2 ? accv2.y : accv2.x,
                                 __ATOMIC_RELAXED, __HIP_MEMORY_SCOPE_AGENT);
    if (own3) __hip_atomic_store(&partial[b * N_PROBESD + 3], pel3 ? accv3.y : accv3.x,
                                 __ATOMIC_RELAXED, __HIP_MEMORY_SCOPE_AGENT);

    // last-arriving block finalizes (counter starts at the 0xAA poison value,
    // so after 8 adds the last block sees 0xAAAAAAAA + 7 -- deterministic,
    // and the re-poison before every timed launch resets it)
    __syncthreads();
    if (tid == 0) {
        __threadfence();
        const unsigned old = __hip_atomic_fetch_add(cnt, 1u, __ATOMIC_ACQ_REL,
                                                    __HIP_MEMORY_SCOPE_AGENT);
        if (old == 0xAAAAAAAAu + (unsigned)(BATCHD - 1)) {
            __threadfence();
            float s0 = 0.f, s1 = 0.f, s2 = 0.f, s3 = 0.f;
            for (int bb = 0; bb < BATCHD; ++bb) {
                s0 += __hip_atomic_load(&partial[bb * N_PROBESD + 0], __ATOMIC_RELAXED, __HIP_MEMORY_SCOPE_AGENT);
                s1 += __hip_atomic_load(&partial[bb * N_PROBESD + 1], __ATOMIC_RELAXED, __HIP_MEMORY_SCOPE_AGENT);
                s2 += __hip_atomic_load(&partial[bb * N_PROBESD + 2], __ATOMIC_RELAXED, __HIP_MEMORY_SCOPE_AGENT);
                s3 += __hip_atomic_load(&partial[bb * N_PROBESD + 3], __ATOMIC_RELAXED, __HIP_MEMORY_SCOPE_AGENT);
            }
            const float inv = 1.0f / (s0 + s1 + s2 + s3);
            out[0] = s0 * inv;
            out[1] = s1 * inv;
            out[2] = s2 * inv;
            out[3] = s3 * inv;
        }
    }
}

extern "C" void kernel_launch(void* const* d_in, const int* in_sizes, int n_in,
                              void* d_out, int out_size, void* d_ws, size_t ws_size,
                              hipStream_t stream) {
    const float* x      = (const float*)d_in[0];
    const float* c      = (const float*)d_in[1];
    const int*   probes = (const int*)d_in[2];
    float* out = (float*)d_out;
    unsigned* cnt  = (unsigned*)d_ws;            // ws[0]: poison 0xAAAAAAAA
    float* partial = (float*)d_ws + 16;          // ws[16..47]: (8,4) partials

    wave_sim<<<BATCHD, 512, 0, stream>>>(x, c, probes, partial, cnt, out);
}

// Round 9
// 242.998 us; speedup vs baseline: 1.0181x; 1.0181x over previous
//
#include <hip/hip_runtime.h>

#define NXD 128
#define NYD 128
#define SRC_XD 64
#define SRC_YD 64
#define T_STEPSD 256
#define BATCHD 8
#define N_PROBESD 4

typedef float v2f __attribute__((ext_vector_type(2)));

// DPP cross-lane single shifts across the full wave64.
// WAVE_SHR1 (0x138): lane i <- lane i-1, lane0 -> 0 (bound_ctrl)
// WAVE_SHL1 (0x130): lane i <- lane i+1, lane63 -> 0
// Zero-fill matches the conv 'SAME' zero padding at col -1 / col 128.
__device__ __forceinline__ float dpp_from_lower(float v) {
    return __int_as_float(__builtin_amdgcn_update_dpp(0, __float_as_int(v), 0x138, 0xF, 0xF, true));
}
__device__ __forceinline__ float dpp_from_upper(float v) {
    return __int_as_float(__builtin_amdgcn_update_dpp(0, __float_as_int(v), 0x130, 0xF, 0xF, true));
}

// Forced packed-FP32 ops (CDNA V_PK_*_F32). Rounds 2-8 plateaued at ~262
// VALU inst/wave/step vs ~135 packed ideal -- consistent with the compiler
// scalarizing v2f arithmetic. These asm micro-ops guarantee packing.
// No early-clobber: dst may alias src (single HW op reads before write).
__device__ __forceinline__ v2f pk_add(v2f a, v2f b) {
    v2f d; asm("v_pk_add_f32 %0, %1, %2" : "=v"(d) : "v"(a), "v"(b)); return d;
}
// dst.lo = a.lo + b.hi ; dst.hi = a.hi + b.lo   (swap of b via op_sel)
__device__ __forceinline__ v2f pk_add_swb(v2f a, v2f b) {
    v2f d; asm("v_pk_add_f32 %0, %1, %2 op_sel:[0,1] op_sel_hi:[1,0]"
               : "=v"(d) : "v"(a), "v"(b)); return d;
}
__device__ __forceinline__ v2f pk_fma(v2f a, v2f b, v2f c) {
    v2f d; asm("v_pk_fma_f32 %0, %1, %2, %3" : "=v"(d) : "v"(a), "v"(b), "v"(c)); return d;
}

// One row update (2 cells): 2 DPP + 6 packed ops.
//   s1 = up + dn;  s2 = {lf,rt} + swap(Y);  s12 = s1 + s2;
//   lap = -4*Y + s12;  u = k*lap + C2;  Z = K2*Z + u
#define ROW(up, dn, Yr, Zr, Kr) { \
    v2f lr; lr.x = dpp_from_lower((Yr).y); lr.y = dpp_from_upper((Yr).x); \
    const v2f s1 = pk_add((up), (dn)); \
    const v2f s2 = pk_add_swb(lr, (Yr)); \
    const v2f s12 = pk_add(s1, s2); \
    const v2f lap = pk_fma((Yr), m4v, s12); \
    const v2f u = pk_fma((Kr), lap, C2v); \
    (Zr) = pk_fma(K2v, (Zr), u); \
}

// Wave-uniform 16-way register select (ro is an SGPR -> scalar branch tree).
#define PSEL(ro, Z, pv) switch (ro) { \
    case 0:  pv = (Z##0);  break; \
    case 1:  pv = (Z##1);  break; \
    case 2:  pv = (Z##2);  break; \
    case 3:  pv = (Z##3);  break; \
    case 4:  pv = (Z##4);  break; \
    case 5:  pv = (Z##5);  break; \
    case 6:  pv = (Z##6);  break; \
    case 7:  pv = (Z##7);  break; \
    case 8:  pv = (Z##8);  break; \
    case 9:  pv = (Z##9);  break; \
    case 10: pv = (Z##10); break; \
    case 11: pv = (Z##11); break; \
    case 12: pv = (Z##12); break; \
    case 13: pv = (Z##13); break; \
    case 14: pv = (Z##14); break; \
    default: pv = (Z##15); break; \
}

// One time step. Halo-dependent rows (0,15) are computed LAST so the
// step-start ds_read latency hides under ROWs 1..14.
// Source add hardcodes (Z##0).x: SRC_XD & 15 == 0, SRC_YD even.
#define STEP(Y, Z, tt) { \
    const int buf_ = (tt) & 1, nb_ = buf_ ^ 1; \
    const v2f ra = *(const v2f*)&haloBot[buf_][wa][colb]; \
    const v2f rb = *(const v2f*)&haloTop[buf_][wb][colb]; \
    ROW(Y##0,  Y##2,  Y##1,  Z##1,  k1) \
    ROW(Y##1,  Y##3,  Y##2,  Z##2,  k2) \
    ROW(Y##2,  Y##4,  Y##3,  Z##3,  k3) \
    ROW(Y##3,  Y##5,  Y##4,  Z##4,  k4) \
    ROW(Y##4,  Y##6,  Y##5,  Z##5,  k5) \
    ROW(Y##5,  Y##7,  Y##6,  Z##6,  k6) \
    ROW(Y##6,  Y##8,  Y##7,  Z##7,  k7) \
    ROW(Y##7,  Y##9,  Y##8,  Z##8,  k8) \
    ROW(Y##8,  Y##10, Y##9,  Z##9,  k9) \
    ROW(Y##9,  Y##11, Y##10, Z##10, k10) \
    ROW(Y##10, Y##12, Y##11, Z##11, k11) \
    ROW(Y##11, Y##13, Y##12, Z##12, k12) \
    ROW(Y##12, Y##14, Y##13, Z##13, k13) \
    ROW(Y##13, Y##15, Y##14, Z##14, k14) \
    ROW(ra,    Y##1,  Y##0,  Z##0,  k0) \
    ROW(Y##14, rb,    Y##15, Z##15, k15) \
    if (has_src) { if (own_src) (Z##0).x += xs[tt]; } \
    if (whas0) { v2f pv; PSEL(pro0s, Z, pv) accv0 += pv * pv; } \
    if (whas1) { v2f pv; PSEL(pro1s, Z, pv) accv1 += pv * pv; } \
    if (whas2) { v2f pv; PSEL(pro2s, Z, pv) accv2 += pv * pv; } \
    if (whas3) { v2f pv; PSEL(pro3s, Z, pv) accv3 += pv * pv; } \
    *(v2f*)&haloTop[nb_][w][colb] = (Z##0); \
    *(v2f*)&haloBot[nb_][w][colb] = (Z##15); \
    __syncthreads(); \
}

// 512 threads = 8 waves = 2/EU = 1 block/CU (grid = 8 blocks, one per batch).
__global__ __launch_bounds__(512)
__attribute__((amdgpu_waves_per_eu(2, 2)))
void wave_sim(
        const float* __restrict__ x,        // (T,B)
        const float* __restrict__ c,        // (NX,NY)
        const int*   __restrict__ probes,   // (4,2) int
        float* __restrict__ partial,        // (B,4) in d_ws
        unsigned*    cnt,                   // d_ws[0], poison-init 0xAAAAAAAA
        float* __restrict__ out)            // (4,)
{
    __shared__ float haloTop[2][9][NYD];    // band row R0;  [8] = zero ghost
    __shared__ float haloBot[2][9][NYD];    // band row R15; [8] = zero ghost
    __shared__ float xs[T_STEPSD];

    const int tid = threadIdx.x;
    const int w = tid >> 6;       // wave 0..7, owns rows 16w..16w+15
    const int l = tid & 63;       // lane, owns cols 2l, 2l+1
    const int b = blockIdx.x;

    const float dt = 0.5f, bdamp = 0.005f;
    const float denom = 1.0f / (dt * dt) + 0.5f * bdamp / dt;  // 4.005
    const float inv_denom = 1.0f / denom;
    const float C2 = 2.0f * inv_denom;
    const float K2 = (-1.0f - dt * bdamp) * inv_denom;
    const float KL = dt * dt * inv_denom;
    v2f C2v; C2v.x = C2;    C2v.y = C2;
    v2f K2v; K2v.x = K2;    K2v.y = K2;
    v2f m4v; m4v.x = -4.0f; m4v.y = -4.0f;
    v2f zz;  zz.x = 0.0f;   zz.y = 0.0f;

    for (int i = tid; i < 2 * 9 * NYD; i += 512) {
        ((float*)haloTop)[i] = 0.0f;
        ((float*)haloBot)[i] = 0.0f;
    }
    if (tid < T_STEPSD) xs[tid] = x[tid * BATCHD + b];

    const int rowbase = w * 16;
    const int colb = 2 * l;
#define LOADK(r) \
    v2f k##r; { \
        const v2f cc = *(const v2f*)&c[(rowbase + r) * NYD + colb]; \
        k##r = KL * cc * cc; \
    }
    LOADK(0) LOADK(1) LOADK(2) LOADK(3) LOADK(4) LOADK(5) LOADK(6) LOADK(7)
    LOADK(8) LOADK(9) LOADK(10) LOADK(11) LOADK(12) LOADK(13) LOADK(14) LOADK(15)
#undef LOADK

    v2f a0 = zz, a1 = zz, a2 = zz, a3 = zz, a4 = zz, a5 = zz, a6 = zz, a7 = zz,
        a8 = zz, a9 = zz, a10 = zz, a11 = zz, a12 = zz, a13 = zz, a14 = zz, a15 = zz;
    v2f b0 = zz, b1 = zz, b2 = zz, b3 = zz, b4 = zz, b5 = zz, b6 = zz, b7 = zz,
        b8 = zz, b9 = zz, b10 = zz, b11 = zz, b12 = zz, b13 = zz, b14 = zz, b15 = zz;

    // probes (wave-uniform coordinates)
    const int px0 = probes[0] & 127, py0 = probes[1] & 127;
    const int px1 = probes[2] & 127, py1 = probes[3] & 127;
    const int px2 = probes[4] & 127, py2 = probes[5] & 127;
    const int px3 = probes[6] & 127, py3 = probes[7] & 127;
    const bool own0 = ((px0 >> 4) == w) && ((py0 >> 1) == l);
    const bool own1 = ((px1 >> 4) == w) && ((py1 >> 1) == l);
    const bool own2 = ((px2 >> 4) == w) && ((py2 >> 1) == l);
    const bool own3 = ((px3 >> 4) == w) && ((py3 >> 1) == l);
    const bool whas0 = __ballot(own0) != 0ULL;
    const bool whas1 = __ballot(own1) != 0ULL;
    const bool whas2 = __ballot(own2) != 0ULL;
    const bool whas3 = __ballot(own3) != 0ULL;
    const int pro0s = __builtin_amdgcn_readfirstlane(px0 & 15);
    const int pro1s = __builtin_amdgcn_readfirstlane(px1 & 15);
    const int pro2s = __builtin_amdgcn_readfirstlane(px2 & 15);
    const int pro3s = __builtin_amdgcn_readfirstlane(px3 & 15);
    const int pel0 = py0 & 1, pel1 = py1 & 1, pel2 = py2 & 1, pel3 = py3 & 1;
    v2f accv0 = zz, accv1 = zz, accv2 = zz, accv3 = zz;

    const bool has_src = (w == (SRC_XD >> 4));            // wave 4 (row 64 = its R0)
    const bool own_src = has_src && (l == (SRC_YD >> 1)); // SRC_YD even -> .x

    const int wa = (w == 0) ? 8 : w - 1;    // 8 = zero ghost slot
    const int wb = (w == 7) ? 8 : w + 1;

    __syncthreads();

#pragma unroll 1
    for (int t = 0; t < T_STEPSD; t += 2) {
        STEP(a, b, t)
        STEP(b, a, t + 1)
    }

    // publish this block's probe sums (agent scope: blocks on different XCDs)
    if (own0) __hip_atomic_store(&partial[b * N_PROBESD + 0], pel0 ? accv0.y : accv0.x,
                                 __ATOMIC_RELAXED, __HIP_MEMORY_SCOPE_AGENT);
    if (own1) __hip_atomic_store(&partial[b * N_PROBESD + 1], pel1 ? accv1.y : accv1.x,
                                 __ATOMIC_RELAXED, __HIP_MEMORY_SCOPE_AGENT);
    if (own2) __hip_atomic_store(&partial[b * N_PROBESD + 2], pel2 ? accv2.y : accv2.x,
                                 __ATOMIC_RELAXED, __HIP_MEMORY_SCOPE_AGENT);
    if (own3) __hip_atomic_store(&partial[b * N_PROBESD + 3], pel3 ? accv3.y : accv3.x,
                                 __ATOMIC_RELAXED, __HIP_MEMORY_SCOPE_AGENT);

    // last-arriving block finalizes (counter starts at the 0xAA poison value;
    // re-poisoned before every timed launch -- deterministic)
    __syncthreads();
    if (tid == 0) {
        __threadfence();
        const unsigned old = __hip_atomic_fetch_add(cnt, 1u, __ATOMIC_ACQ_REL,
                                                    __HIP_MEMORY_SCOPE_AGENT);
        if (old == 0xAAAAAAAAu + (unsigned)(BATCHD - 1)) {
            __threadfence();
            float s0 = 0.f, s1 = 0.f, s2 = 0.f, s3 = 0.f;
            for (int bb = 0; bb < BATCHD; ++bb) {
                s0 += __hip_atomic_load(&partial[bb * N_PROBESD + 0], __ATOMIC_RELAXED, __HIP_MEMORY_SCOPE_AGENT);
                s1 += __hip_atomic_load(&partial[bb * N_PROBESD + 1], __ATOMIC_RELAXED, __HIP_MEMORY_SCOPE_AGENT);
                s2 += __hip_atomic_load(&partial[bb * N_PROBESD + 2], __ATOMIC_RELAXED, __HIP_MEMORY_SCOPE_AGENT);
                s3 += __hip_atomic_load(&partial[bb * N_PROBESD + 3], __ATOMIC_RELAXED, __HIP_MEMORY_SCOPE_AGENT);
            }
            const float inv = 1.0f / (s0 + s1 + s2 + s3);
            out[0] = s0 * inv;
            out[1] = s1 * inv;
            out[2] = s2 * inv;
            out[3] = s3 * inv;
        }
    }
}

extern "C" void kernel_launch(void* const* d_in, const int* in_sizes, int n_in,
                              void* d_out, int out_size, void* d_ws, size_t ws_size,
                              hipStream_t stream) {
    const float* x      = (const float*)d_in[0];
    const float* c      = (const float*)d_in[1];
    const int*   probes = (const int*)d_in[2];
    float* out = (float*)d_out;
    unsigned* cnt  = (unsigned*)d_ws;            // ws[0]: poison 0xAAAAAAAA
    float* partial = (float*)d_ws + 16;          // ws[16..47]: (8,4) partials

    wave_sim<<<BATCHD, 512, 0, stream>>>(x, c, probes, partial, cnt, out);
}

// Round 10
// 231.062 us; speedup vs baseline: 1.0707x; 1.0517x over previous
//
#include <hip/hip_runtime.h>

#define NXD 128
#define NYD 128
#define SRC_XD 64
#define SRC_YD 64
#define T_STEPSD 256
#define BATCHD 8
#define N_PROBESD 4

typedef float v2f __attribute__((ext_vector_type(2)));

// DPP cross-lane single shifts across the full wave64.
// WAVE_SHR1 (0x138): lane i <- lane i-1, lane0 -> 0 (bound_ctrl)
// WAVE_SHL1 (0x130): lane i <- lane i+1, lane63 -> 0
// Zero-fill matches the conv 'SAME' zero padding at col -1 / col 128.
__device__ __forceinline__ float dpp_from_lower(float v) {
    return __int_as_float(__builtin_amdgcn_update_dpp(0, __float_as_int(v), 0x138, 0xF, 0xF, true));
}
__device__ __forceinline__ float dpp_from_upper(float v) {
    return __int_as_float(__builtin_amdgcn_update_dpp(0, __float_as_int(v), 0x130, 0xF, 0xF, true));
}

// One row update (2 cells), compiler-scheduled (R9 proved inline-asm packing
// does NOT reduce issue time -- the compiler already packs; asm only added
// constant-materialization and scheduling overhead).
//   lap = up + dn + {lf+Y.y, Y.x+rt} - 4Y ;  Z = K*lap + (C2 + K2*Z)
#define ROW(up, dn, Yr, Zr, Kr) { \
    const float lf = dpp_from_lower((Yr).y); \
    const float rt = dpp_from_upper((Yr).x); \
    v2f cross; cross.x = lf + (Yr).y; cross.y = (Yr).x + rt; \
    const v2f lap = (up) + (dn) + cross - 4.0f * (Yr); \
    (Zr) = (Kr) * lap + (C2v + K2v * (Zr)); \
}

// Wave-uniform 16-way register select (ro is an SGPR -> scalar branch tree).
#define PSEL(ro, Z, pv) switch (ro) { \
    case 0:  pv = (Z##0);  break; \
    case 1:  pv = (Z##1);  break; \
    case 2:  pv = (Z##2);  break; \
    case 3:  pv = (Z##3);  break; \
    case 4:  pv = (Z##4);  break; \
    case 5:  pv = (Z##5);  break; \
    case 6:  pv = (Z##6);  break; \
    case 7:  pv = (Z##7);  break; \
    case 8:  pv = (Z##8);  break; \
    case 9:  pv = (Z##9);  break; \
    case 10: pv = (Z##10); break; \
    case 11: pv = (Z##11); break; \
    case 12: pv = (Z##12); break; \
    case 13: pv = (Z##13); break; \
    case 14: pv = (Z##14); break; \
    default: pv = (Z##15); break; \
}

// One time step: Y = current (read-only), Z = previous, overwritten with new.
// Source add hardcodes (Z##0).x: SRC_XD & 15 == 0, SRC_YD even.
#define STEP(Y, Z, tt) { \
    const int buf_ = (tt) & 1, nb_ = buf_ ^ 1; \
    const v2f ra = *(const v2f*)&haloBot[buf_][wa][colb]; \
    const v2f rb = *(const v2f*)&haloTop[buf_][wb][colb]; \
    ROW(ra,    Y##1,  Y##0,  Z##0,  k0) \
    ROW(Y##0,  Y##2,  Y##1,  Z##1,  k1) \
    ROW(Y##1,  Y##3,  Y##2,  Z##2,  k2) \
    ROW(Y##2,  Y##4,  Y##3,  Z##3,  k3) \
    ROW(Y##3,  Y##5,  Y##4,  Z##4,  k4) \
    ROW(Y##4,  Y##6,  Y##5,  Z##5,  k5) \
    ROW(Y##5,  Y##7,  Y##6,  Z##6,  k6) \
    ROW(Y##6,  Y##8,  Y##7,  Z##7,  k7) \
    ROW(Y##7,  Y##9,  Y##8,  Z##8,  k8) \
    ROW(Y##8,  Y##10, Y##9,  Z##9,  k9) \
    ROW(Y##9,  Y##11, Y##10, Z##10, k10) \
    ROW(Y##10, Y##12, Y##11, Z##11, k11) \
    ROW(Y##11, Y##13, Y##12, Z##12, k12) \
    ROW(Y##12, Y##14, Y##13, Z##13, k13) \
    ROW(Y##13, Y##15, Y##14, Z##14, k14) \
    ROW(Y##14, rb,    Y##15, Z##15, k15) \
    if (has_src) { if (own_src) (Z##0).x += xs[tt]; } \
    if (whas0) { v2f pv; PSEL(pro0s, Z, pv) accv0 += pv * pv; } \
    if (whas1) { v2f pv; PSEL(pro1s, Z, pv) accv1 += pv * pv; } \
    if (whas2) { v2f pv; PSEL(pro2s, Z, pv) accv2 += pv * pv; } \
    if (whas3) { v2f pv; PSEL(pro3s, Z, pv) accv3 += pv * pv; } \
    *(v2f*)&haloTop[nb_][w][colb] = (Z##0); \
    *(v2f*)&haloBot[nb_][w][colb] = (Z##15); \
    __syncthreads(); \
}

// 512 threads = 8 waves = 2/EU = 1 block/CU (grid = 8 blocks, one per batch).
// This is the measured-best configuration (R5: 176.8 us kernel); R6-R9
// alternatives (2-step fusion, 4 waves/EU, k-in-LDS, forced v_pk asm) were
// all neutral-to-worse -- per-CU VALU issue time is invariant ~108 us and
// the rest is latency at 2 waves/SIMD.
__global__ __launch_bounds__(512)
__attribute__((amdgpu_waves_per_eu(2, 2)))
void wave_sim(
        const float* __restrict__ x,        // (T,B)
        const float* __restrict__ c,        // (NX,NY)
        const int*   __restrict__ probes,   // (4,2) int
        float* __restrict__ partial,        // (B,4) in d_ws
        unsigned*    cnt,                   // d_ws[0], poison-init 0xAAAAAAAA
        float* __restrict__ out)            // (4,)
{
    __shared__ float haloTop[2][9][NYD];    // band row R0;  [8] = zero ghost
    __shared__ float haloBot[2][9][NYD];    // band row R15; [8] = zero ghost
    __shared__ float xs[T_STEPSD];

    const int tid = threadIdx.x;
    const int w = tid >> 6;       // wave 0..7, owns rows 16w..16w+15
    const int l = tid & 63;       // lane, owns cols 2l, 2l+1
    const int b = blockIdx.x;

    const float dt = 0.5f, bdamp = 0.005f;
    const float denom = 1.0f / (dt * dt) + 0.5f * bdamp / dt;  // 4.005
    const float inv_denom = 1.0f / denom;
    const float C2 = 2.0f * inv_denom;
    const float K2 = (-1.0f - dt * bdamp) * inv_denom;
    const float KL = dt * dt * inv_denom;
    v2f C2v; C2v.x = C2; C2v.y = C2;
    v2f K2v; K2v.x = K2; K2v.y = K2;
    v2f zz;  zz.x = 0.0f; zz.y = 0.0f;

    for (int i = tid; i < 2 * 9 * NYD; i += 512) {
        ((float*)haloTop)[i] = 0.0f;
        ((float*)haloBot)[i] = 0.0f;
    }
    if (tid < T_STEPSD) xs[tid] = x[tid * BATCHD + b];

    const int rowbase = w * 16;
    const int colb = 2 * l;
#define LOADK(r) \
    v2f k##r; { \
        const v2f cc = *(const v2f*)&c[(rowbase + r) * NYD + colb]; \
        k##r = KL * cc * cc; \
    }
    LOADK(0) LOADK(1) LOADK(2) LOADK(3) LOADK(4) LOADK(5) LOADK(6) LOADK(7)
    LOADK(8) LOADK(9) LOADK(10) LOADK(11) LOADK(12) LOADK(13) LOADK(14) LOADK(15)
#undef LOADK

    v2f a0 = zz, a1 = zz, a2 = zz, a3 = zz, a4 = zz, a5 = zz, a6 = zz, a7 = zz,
        a8 = zz, a9 = zz, a10 = zz, a11 = zz, a12 = zz, a13 = zz, a14 = zz, a15 = zz;
    v2f b0 = zz, b1 = zz, b2 = zz, b3 = zz, b4 = zz, b5 = zz, b6 = zz, b7 = zz,
        b8 = zz, b9 = zz, b10 = zz, b11 = zz, b12 = zz, b13 = zz, b14 = zz, b15 = zz;

    // probes (wave-uniform coordinates)
    const int px0 = probes[0] & 127, py0 = probes[1] & 127;
    const int px1 = probes[2] & 127, py1 = probes[3] & 127;
    const int px2 = probes[4] & 127, py2 = probes[5] & 127;
    const int px3 = probes[6] & 127, py3 = probes[7] & 127;
    const bool own0 = ((px0 >> 4) == w) && ((py0 >> 1) == l);
    const bool own1 = ((px1 >> 4) == w) && ((py1 >> 1) == l);
    const bool own2 = ((px2 >> 4) == w) && ((py2 >> 1) == l);
    const bool own3 = ((px3 >> 4) == w) && ((py3 >> 1) == l);
    const bool whas0 = __ballot(own0) != 0ULL;
    const bool whas1 = __ballot(own1) != 0ULL;
    const bool whas2 = __ballot(own2) != 0ULL;
    const bool whas3 = __ballot(own3) != 0ULL;
    const int pro0s = __builtin_amdgcn_readfirstlane(px0 & 15);
    const int pro1s = __builtin_amdgcn_readfirstlane(px1 & 15);
    const int pro2s = __builtin_amdgcn_readfirstlane(px2 & 15);
    const int pro3s = __builtin_amdgcn_readfirstlane(px3 & 15);
    const int pel0 = py0 & 1, pel1 = py1 & 1, pel2 = py2 & 1, pel3 = py3 & 1;
    v2f accv0 = zz, accv1 = zz, accv2 = zz, accv3 = zz;

    const bool has_src = (w == (SRC_XD >> 4));            // wave 4 (row 64 = its R0)
    const bool own_src = has_src && (l == (SRC_YD >> 1)); // SRC_YD even -> .x

    const int wa = (w == 0) ? 8 : w - 1;    // 8 = zero ghost slot
    const int wb = (w == 7) ? 8 : w + 1;

    __syncthreads();

#pragma unroll 1
    for (int t = 0; t < T_STEPSD; t += 2) {
        STEP(a, b, t)
        STEP(b, a, t + 1)
    }

    // publish this block's probe sums (agent scope: blocks on different XCDs)
    if (own0) __hip_atomic_store(&partial[b * N_PROBESD + 0], pel0 ? accv0.y : accv0.x,
                                 __ATOMIC_RELAXED, __HIP_MEMORY_SCOPE_AGENT);
    if (own1) __hip_atomic_store(&partial[b * N_PROBESD + 1], pel1 ? accv1.y : accv1.x,
                                 __ATOMIC_RELAXED, __HIP_MEMORY_SCOPE_AGENT);
    if (own2) __hip_atomic_store(&partial[b * N_PROBESD + 2], pel2 ? accv2.y : accv2.x,
                                 __ATOMIC_RELAXED, __HIP_MEMORY_SCOPE_AGENT);
    if (own3) __hip_atomic_store(&partial[b * N_PROBESD + 3], pel3 ? accv3.y : accv3.x,
                                 __ATOMIC_RELAXED, __HIP_MEMORY_SCOPE_AGENT);

    // last-arriving block finalizes (counter starts at the 0xAA poison value;
    // re-poisoned before every timed launch -- deterministic; verified R8/R9)
    __syncthreads();
    if (tid == 0) {
        __threadfence();
        const unsigned old = __hip_atomic_fetch_add(cnt, 1u, __ATOMIC_ACQ_REL,
                                                    __HIP_MEMORY_SCOPE_AGENT);
        if (old == 0xAAAAAAAAu + (unsigned)(BATCHD - 1)) {
            __threadfence();
            float s0 = 0.f, s1 = 0.f, s2 = 0.f, s3 = 0.f;
            for (int bb = 0; bb < BATCHD; ++bb) {
                s0 += __hip_atomic_load(&partial[bb * N_PROBESD + 0], __ATOMIC_RELAXED, __HIP_MEMORY_SCOPE_AGENT);
                s1 += __hip_atomic_load(&partial[bb * N_PROBESD + 1], __ATOMIC_RELAXED, __HIP_MEMORY_SCOPE_AGENT);
                s2 += __hip_atomic_load(&partial[bb * N_PROBESD + 2], __ATOMIC_RELAXED, __HIP_MEMORY_SCOPE_AGENT);
                s3 += __hip_atomic_load(&partial[bb * N_PROBESD + 3], __ATOMIC_RELAXED, __HIP_MEMORY_SCOPE_AGENT);
            }
            const float inv = 1.0f / (s0 + s1 + s2 + s3);
            out[0] = s0 * inv;
            out[1] = s1 * inv;
            out[2] = s2 * inv;
            out[3] = s3 * inv;
        }
    }
}

extern "C" void kernel_launch(void* const* d_in, const int* in_sizes, int n_in,
                              void* d_out, int out_size, void* d_ws, size_t ws_size,
                              hipStream_t stream) {
    const float* x      = (const float*)d_in[0];
    const float* c      = (const float*)d_in[1];
    const int*   probes = (const int*)d_in[2];
    float* out = (float*)d_out;
    unsigned* cnt  = (unsigned*)d_ws;            // ws[0]: poison 0xAAAAAAAA
    float* partial = (float*)d_ws + 16;          // ws[16..47]: (8,4) partials

    wave_sim<<<BATCHD, 512, 0, stream>>>(x, c, probes, partial, cnt, out);
}